// Round 2
// baseline (1167.158 us; speedup 1.0000x reference)
//
#include <hip/hip_runtime.h>
#include <hip/hip_bf16.h>
#include <cmath>

// Problem constants
constexpr int Bn  = 4;
constexpr int Sn  = 4096;
constexpr int En  = 1024;
constexpr int Hn  = 16;
constexpr int HD  = 64;
constexpr int WSZ = 128;
constexpr int NW  = Sn / WSZ;   // 32
constexpr int Mr  = Bn * Sn;    // 16384 rows
constexpr int N3  = 3 * En;     // 3072
constexpr int Kd  = En;         // 1024

typedef __attribute__((ext_vector_type(8))) short  bf16x8;
typedef __attribute__((ext_vector_type(4))) float  f32x4;
typedef __attribute__((ext_vector_type(8))) unsigned short ushort8;

__device__ __forceinline__ unsigned short f2bf(float f) {
  __hip_bfloat16 h = __float2bfloat16(f);   // RTNE
  return *reinterpret_cast<unsigned short*>(&h);
}

__device__ __forceinline__ void gload_lds16(const void* g, void* l) {
  __builtin_amdgcn_global_load_lds(
      (const __attribute__((address_space(1))) void*)g,
      (__attribute__((address_space(3))) void*)l, 16, 0, 0);
}

// ---------------------------------------------------------------------------
// cvt_x: x fp32 [16384,1024] -> bf16 (row-major, same layout)
// ---------------------------------------------------------------------------
__global__ __launch_bounds__(256) void cvt_x(const float* __restrict__ x,
                                             unsigned short* __restrict__ xb) {
  const int i = (blockIdx.x * 256 + threadIdx.x) * 8;
  const float4 a = *(const float4*)&x[i];
  const float4 b = *(const float4*)&x[i + 4];
  ushort8 o;
  o[0] = f2bf(a.x); o[1] = f2bf(a.y); o[2] = f2bf(a.z); o[3] = f2bf(a.w);
  o[4] = f2bf(b.x); o[5] = f2bf(b.y); o[6] = f2bf(b.z); o[7] = f2bf(b.w);
  *(ushort8*)&xb[i] = o;
}

// ---------------------------------------------------------------------------
// cvt_wT: W fp32 [K=1024][N=3072] -> Wt bf16 [N=3072][K=1024]  (transpose)
// 32x32 LDS tile, 256 threads.
// ---------------------------------------------------------------------------
__global__ __launch_bounds__(256) void cvt_wT(const float* __restrict__ W,
                                              unsigned short* __restrict__ Wt) {
  __shared__ float t[32][33];
  const int bx = blockIdx.x * 32;          // n base
  const int by = blockIdx.y * 32;          // k base
  const int tx = threadIdx.x & 31;
  const int ty = threadIdx.x >> 5;         // 0..7
  #pragma unroll
  for (int i = 0; i < 32; i += 8)
    t[ty + i][tx] = W[(size_t)(by + ty + i) * N3 + bx + tx];
  __syncthreads();
  #pragma unroll
  for (int i = 0; i < 32; i += 8)
    Wt[(size_t)(bx + ty + i) * Kd + by + tx] = f2bf(t[tx][ty + i]);
}

// ---------------------------------------------------------------------------
// qkv_gemm_bf16: C[16384][3072] = A[16384][1024](bf16) @ Wt^T + bias, fp32 out
// m97 structure: 128x128 tile, BK=32, 4 waves, global_load_lds(16B),
// mfma_f32_16x16x32_bf16, both LDS tiles [row][k] linear.
// Frag layouts (m89/m91 HW-verified): A lane l -> row=l&15, k=(l>>4)*8+j;
// B(=Wt row) lane l -> col=l&15, k=(l>>4)*8+j; D: row=(l>>4)*4+r, col=l&15.
// ---------------------------------------------------------------------------
constexpr int TM = 128, TN = 128, TK = 32;

__global__ __launch_bounds__(256) void qkv_gemm_bf16(
    const unsigned short* __restrict__ Abf,   // [Mr][Kd]
    const unsigned short* __restrict__ Bt,    // [N3][Kd]  (= W^T)
    const float* __restrict__ bias, float* __restrict__ C) {
  __shared__ unsigned short As[TM * TK];      // 8 KiB
  __shared__ unsigned short Bs[TN * TK];      // 8 KiB

  const int tid  = threadIdx.x;
  const int wave = tid >> 6;
  const int lane = tid & 63;
  const int bm = blockIdx.y * TM;
  const int bn = blockIdx.x * TN;
  const int wr = wave >> 1, wc = wave & 1;    // 2x2 wave grid, 64x64 each

  f32x4 acc[4][4] = {};

  // staging: chunk c = wave*2+i covers tile rows [c*16, c*16+16)
  const int sr  = lane >> 2;                  // row within chunk
  const int sc8 = (lane & 3) * 8;             // elem offset within row

  const int fr = lane & 15;
  const int fk = (lane >> 4) * 8;

  for (int k0 = 0; k0 < Kd; k0 += TK) {
    #pragma unroll
    for (int i = 0; i < 2; ++i) {
      const int c = wave * 2 + i;
      const unsigned short* ga =
          Abf + (size_t)(bm + c * 16 + sr) * Kd + k0 + sc8;
      const unsigned short* gb =
          Bt + (size_t)(bn + c * 16 + sr) * Kd + k0 + sc8;
      gload_lds16(ga, &As[c * 512]);
      gload_lds16(gb, &Bs[c * 512]);
    }
    __syncthreads();   // compiler drains vmcnt before s_barrier

    bf16x8 af[4], bfr[4];
    #pragma unroll
    for (int m = 0; m < 4; ++m)
      af[m] = *(const bf16x8*)&As[(wr * 64 + m * 16 + fr) * TK + fk];
    #pragma unroll
    for (int n = 0; n < 4; ++n)
      bfr[n] = *(const bf16x8*)&Bs[(wc * 64 + n * 16 + fr) * TK + fk];
    #pragma unroll
    for (int m = 0; m < 4; ++m)
      #pragma unroll
      for (int n = 0; n < 4; ++n)
        acc[m][n] = __builtin_amdgcn_mfma_f32_16x16x32_bf16(
            af[m], bfr[n], acc[m][n], 0, 0, 0);
    __syncthreads();
  }

  // epilogue: D row=(lane>>4)*4+r, col=lane&15
  const int col0 = bn + wc * 64 + (lane & 15);
  const int row0 = bm + wr * 64 + (lane >> 4) * 4;
  #pragma unroll
  for (int n = 0; n < 4; ++n) {
    const int col = col0 + n * 16;
    const float bv = bias[col];
    #pragma unroll
    for (int m = 0; m < 4; ++m) {
      #pragma unroll
      for (int r = 0; r < 4; ++r)
        C[(size_t)(row0 + m * 16 + r) * N3 + col] = acc[m][n][r] + bv;
    }
  }
}

// ---------------------------------------------------------------------------
// Kernel 2: local windowed attention, fp32, online softmax (unchanged R1).
// Border windows attend to 128 unmasked all-(-1) K/V pad rows (reference's
// collect_windows semantics) — handled analytically.
// ---------------------------------------------------------------------------
constexpr int CH = 64;

__global__ __launch_bounds__(128) void local_attn(
    const float* __restrict__ qkv, float* __restrict__ out) {
  const int w  = blockIdx.x;
  const int bh = blockIdx.y;
  const int b  = bh / Hn;
  const int h  = bh % Hn;
  const int p  = threadIdx.x;

  __shared__ float Ks[CH][HD];
  __shared__ float Vs[CH][HD];

  const size_t qoff = ((size_t)(b * Sn + w * WSZ + p)) * N3 + h * HD;
  float q[HD];
  #pragma unroll
  for (int d = 0; d < HD; d += 4) {
    const float4 t = *(const float4*)&qkv[qoff + d];
    q[d] = t.x; q[d + 1] = t.y; q[d + 2] = t.z; q[d + 3] = t.w;
  }

  float m_run = -INFINITY, l_run = 0.f;
  float acc[HD];
  #pragma unroll
  for (int d = 0; d < HD; ++d) acc[d] = 0.f;

  for (int c = 0; c < 3; ++c) {
    const int wk = w + c - 1;
    if (wk < 0 || wk >= NW) {
      float s = 0.f;
      #pragma unroll
      for (int d = 0; d < HD; ++d) s -= q[d];
      if (s > m_run) {
        const float corr = __expf(m_run - s);
        l_run *= corr;
        #pragma unroll
        for (int d = 0; d < HD; ++d) acc[d] *= corr;
        m_run = s;
      }
      const float pe = __expf(s - m_run) * 128.f;
      l_run += pe;
      #pragma unroll
      for (int d = 0; d < HD; ++d) acc[d] -= pe;
      continue;
    }
    for (int sc = 0; sc < WSZ / CH; ++sc) {
      const int r = p >> 1;
      const int half = (p & 1) * 32;
      const size_t koff =
          ((size_t)(b * Sn + wk * WSZ + sc * CH + r)) * N3 + En + h * HD + half;
      #pragma unroll
      for (int d4 = 0; d4 < 8; ++d4) {
        *(float4*)&Ks[r][half + d4 * 4] = *(const float4*)&qkv[koff + d4 * 4];
        *(float4*)&Vs[r][half + d4 * 4] = *(const float4*)&qkv[koff + En + d4 * 4];
      }
      __syncthreads();
      const int kb = sc * CH;
      for (int kk = 0; kk < CH; ++kk) {
        float s = 0.f;
        #pragma unroll
        for (int d = 0; d < HD; ++d) s += q[d] * Ks[kk][d];
        const int kabs = kb + kk;
        const bool ok =
            (c == 1) || (c == 0 && p <= kabs) || (c == 2 && kabs <= p);
        if (ok) {
          if (s > m_run) {
            const float corr = __expf(m_run - s);
            l_run *= corr;
            #pragma unroll
            for (int d = 0; d < HD; ++d) acc[d] *= corr;
            m_run = s;
          }
          const float pe = __expf(s - m_run);
          l_run += pe;
          #pragma unroll
          for (int d = 0; d < HD; ++d) acc[d] += pe * Vs[kk][d];
        }
      }
      __syncthreads();
    }
  }

  const float inv = 1.f / l_run;
  const size_t ooff = ((size_t)(b * Sn + w * WSZ + p)) * En + h * HD;
  #pragma unroll
  for (int d = 0; d < HD; d += 4) {
    float4 o;
    o.x = acc[d] * inv;
    o.y = acc[d + 1] * inv;
    o.z = acc[d + 2] * inv;
    o.w = acc[d + 3] * inv;
    *(float4*)&out[ooff + d] = o;
  }
}

// ---------------------------------------------------------------------------
extern "C" void kernel_launch(void* const* d_in, const int* in_sizes, int n_in,
                              void* d_out, int out_size, void* d_ws,
                              size_t ws_size, hipStream_t stream) {
  const float* x    = (const float*)d_in[0];
  const float* wqkv = (const float*)d_in[1];
  const float* bqkv = (const float*)d_in[2];
  float* out = (float*)d_out;

  // ws layout: qkv f32 (201.3 MB) | xb bf16 (33.6 MB) | wb bf16 (6.3 MB)
  char* ws = (char*)d_ws;
  float* qkv = (float*)ws;
  unsigned short* xb = (unsigned short*)(ws + (size_t)Mr * N3 * 4);
  unsigned short* wb = (unsigned short*)(ws + (size_t)Mr * N3 * 4 +
                                         (size_t)Mr * Kd * 2);

  cvt_x<<<(Mr * Kd) / (256 * 8), 256, 0, stream>>>(x, xb);
  dim3 gw(N3 / 32, Kd / 32);
  cvt_wT<<<gw, 256, 0, stream>>>(wqkv, wb);

  dim3 g1(N3 / TN, Mr / TM);                 // (24,128)
  qkv_gemm_bf16<<<g1, 256, 0, stream>>>(xb, wb, bqkv, qkv);

  dim3 g2(NW, Bn * Hn);                      // (32,64)
  local_attn<<<g2, 128, 0, stream>>>(qkv, out);
}

// Round 3
// 415.841 us; speedup vs baseline: 2.8067x; 2.8067x over previous
//
#include <hip/hip_runtime.h>
#include <hip/hip_bf16.h>
#include <cmath>

// Problem constants
constexpr int Bn  = 4;
constexpr int Sn  = 4096;
constexpr int En  = 1024;
constexpr int Hn  = 16;
constexpr int HD  = 64;
constexpr int WSZ = 128;
constexpr int NW  = Sn / WSZ;   // 32
constexpr int Mr  = Bn * Sn;    // 16384 rows
constexpr int N3  = 3 * En;     // 3072
constexpr int Kd  = En;         // 1024

typedef __attribute__((ext_vector_type(8))) short  bf16x8;
typedef __attribute__((ext_vector_type(4))) float  f32x4;
typedef __attribute__((ext_vector_type(8))) unsigned short ushort8;

__device__ __forceinline__ unsigned short f2bf(float f) {
  __hip_bfloat16 h = __float2bfloat16(f);   // RTNE
  return *reinterpret_cast<unsigned short*>(&h);
}

__device__ __forceinline__ void gload_lds16(const void* g, void* l) {
  __builtin_amdgcn_global_load_lds(
      (const __attribute__((address_space(1))) void*)g,
      (__attribute__((address_space(3))) void*)l, 16, 0, 0);
}

// ---------------------------------------------------------------------------
// cvt_x: x fp32 [16384,1024] -> bf16 (row-major)
// ---------------------------------------------------------------------------
__global__ __launch_bounds__(256) void cvt_x(const float* __restrict__ x,
                                             unsigned short* __restrict__ xb) {
  const int i = (blockIdx.x * 256 + threadIdx.x) * 8;
  const float4 a = *(const float4*)&x[i];
  const float4 b = *(const float4*)&x[i + 4];
  ushort8 o;
  o[0] = f2bf(a.x); o[1] = f2bf(a.y); o[2] = f2bf(a.z); o[3] = f2bf(a.w);
  o[4] = f2bf(b.x); o[5] = f2bf(b.y); o[6] = f2bf(b.z); o[7] = f2bf(b.w);
  *(ushort8*)&xb[i] = o;
}

// ---------------------------------------------------------------------------
// cvt_wT: W fp32 [K=1024][N=3072] -> Wt bf16 [N=3072][K=1024]  (transpose)
// ---------------------------------------------------------------------------
__global__ __launch_bounds__(256) void cvt_wT(const float* __restrict__ W,
                                              unsigned short* __restrict__ Wt) {
  __shared__ float t[32][33];
  const int bx = blockIdx.x * 32;          // n base
  const int by = blockIdx.y * 32;          // k base
  const int tx = threadIdx.x & 31;
  const int ty = threadIdx.x >> 5;
  #pragma unroll
  for (int i = 0; i < 32; i += 8)
    t[ty + i][tx] = W[(size_t)(by + ty + i) * N3 + bx + tx];
  __syncthreads();
  #pragma unroll
  for (int i = 0; i < 32; i += 8)
    Wt[(size_t)(bx + ty + i) * Kd + by + tx] = f2bf(t[tx][ty + i]);
}

// ---------------------------------------------------------------------------
// qkv_gemm_bf16: C = A(bf16) @ W^T(bf16) + bias. Epilogue scatters bf16
// Q/K/V tensors in [b*16+h][s][d] layout (head-major) for the attn kernel.
// m97 structure unchanged from R2 (verified).
// ---------------------------------------------------------------------------
constexpr int TM = 128, TN = 128, TK = 32;

__global__ __launch_bounds__(256) void qkv_gemm_bf16(
    const unsigned short* __restrict__ Abf,   // [Mr][Kd]
    const unsigned short* __restrict__ Bt,    // [N3][Kd]
    const float* __restrict__ bias,
    unsigned short* __restrict__ Qb, unsigned short* __restrict__ Kb,
    unsigned short* __restrict__ Vb) {
  __shared__ unsigned short As[TM * TK];
  __shared__ unsigned short Bs[TN * TK];

  const int tid  = threadIdx.x;
  const int wave = tid >> 6;
  const int lane = tid & 63;
  const int bm = blockIdx.y * TM;
  const int bn = blockIdx.x * TN;
  const int wr = wave >> 1, wc = wave & 1;

  f32x4 acc[4][4] = {};

  const int sr  = lane >> 2;
  const int sc8 = (lane & 3) * 8;
  const int fr = lane & 15;
  const int fk = (lane >> 4) * 8;

  for (int k0 = 0; k0 < Kd; k0 += TK) {
    #pragma unroll
    for (int i = 0; i < 2; ++i) {
      const int c = wave * 2 + i;
      gload_lds16(Abf + (size_t)(bm + c * 16 + sr) * Kd + k0 + sc8, &As[c * 512]);
      gload_lds16(Bt  + (size_t)(bn + c * 16 + sr) * Kd + k0 + sc8, &Bs[c * 512]);
    }
    __syncthreads();
    bf16x8 af[4], bfr[4];
    #pragma unroll
    for (int m = 0; m < 4; ++m)
      af[m] = *(const bf16x8*)&As[(wr * 64 + m * 16 + fr) * TK + fk];
    #pragma unroll
    for (int n = 0; n < 4; ++n)
      bfr[n] = *(const bf16x8*)&Bs[(wc * 64 + n * 16 + fr) * TK + fk];
    #pragma unroll
    for (int m = 0; m < 4; ++m)
      #pragma unroll
      for (int n = 0; n < 4; ++n)
        acc[m][n] = __builtin_amdgcn_mfma_f32_16x16x32_bf16(
            af[m], bfr[n], acc[m][n], 0, 0, 0);
    __syncthreads();
  }

  // epilogue: D row=(lane>>4)*4+r, col=lane&15 — scatter to head-major bf16
  const int col0 = bn + wc * 64 + (lane & 15);
  const int row0 = bm + wr * 64 + (lane >> 4) * 4;
  #pragma unroll
  for (int n = 0; n < 4; ++n) {
    const int col = col0 + n * 16;
    const float bv = bias[col];
    const int which = col >> 10;           // 0=q 1=k 2=v (uniform per n)
    const int h = (col >> 6) & 15;
    const int d = col & 63;
    unsigned short* T = (which == 0) ? Qb : (which == 1) ? Kb : Vb;
    #pragma unroll
    for (int m = 0; m < 4; ++m)
      #pragma unroll
      for (int r = 0; r < 4; ++r) {
        const int row = row0 + m * 16 + r;
        const int b = row >> 12;
        const int s = row & 4095;
        T[((size_t)((b << 4) + h) * Sn + s) * HD + d] =
            f2bf(acc[m][n][r] + bv);
      }
  }
}

// ---------------------------------------------------------------------------
// attn_mfma: flash-style local attention, MFMA 16x16x32 bf16.
// Block = one (bh, window): 256 threads = 4 waves, wave owns 32 query rows.
// LDS tiles [row][64d] with XOR swizzle byte^=((row&7)<<4) (G4; rule #21:
// linear gload_lds dest + inverse-swizzled global src + swizzled reads).
// Border windows: 128 unmasked all-(-1) pad K/V rows -> analytic via
// Q row-sums (MFMA against all-ones B).
// ---------------------------------------------------------------------------
__global__ __launch_bounds__(256) void attn_mfma(
    const unsigned short* __restrict__ Qb,
    const unsigned short* __restrict__ Kb,
    const unsigned short* __restrict__ Vb,
    float* __restrict__ out) {
  __shared__ unsigned short Qs[128 * 64];   // 16 KB
  __shared__ unsigned short Ks[64 * 64];    //  8 KB
  __shared__ unsigned short Vt[64 * 64];    //  8 KB ([d][key], swizzled)
  __shared__ unsigned short Ps[4][32 * 72]; // 18 KB (stride 72: 16B-aligned, conflict-free)

  const int w   = blockIdx.x;
  const int bh  = blockIdx.y;
  const int tid = threadIdx.x, wave = tid >> 6, lane = tid & 63;
  const int gl = lane >> 4;                 // lane group 0..3
  const int li = lane & 15;
  const int q0 = wave * 32;

  const size_t head_off = (size_t)bh * Sn * HD;
  const unsigned short* Qg = Qb + head_off + (size_t)w * WSZ * HD;

  // --- stage Q (16 KB contiguous, pre-swizzled source) ---
  const int rsub = lane >> 3;                       // row within 8-row chunk
  const int bsub = ((lane & 7) ^ rsub) << 3;        // swizzled elem offset
  #pragma unroll
  for (int i = 0; i < 4; ++i) {
    const int c = wave * 4 + i;                     // 16 chunks x 8 rows
    gload_lds16(Qg + (size_t)(c * 8 + rsub) * HD + bsub, &Qs[c * 512]);
  }
  __syncthreads();

  // swizzled frag read: row-major [row][64] bf16, XOR ((row&7)<<4)
  auto lds_frag = [&](const unsigned short* base, int row, int kpos) {
    return *(const bf16x8*)((const char*)base + row * 128 +
                            ((kpos * 2) ^ ((row & 7) << 4)));
  };

  // Q row sums (for pad windows): D = Q * ones
  bf16x8 ones;
  #pragma unroll
  for (int j = 0; j < 8; ++j) ones[j] = (short)0x3F80;   // bf16 1.0
  f32x4 qsum[2] = {};
  #pragma unroll
  for (int m = 0; m < 2; ++m)
    #pragma unroll
    for (int ks = 0; ks < 2; ++ks)
      qsum[m] = __builtin_amdgcn_mfma_f32_16x16x32_bf16(
          lds_frag(Qs, q0 + m * 16 + li, ks * 32 + gl * 8), ones, qsum[m], 0, 0, 0);

  f32x4 acc[2][4] = {};
  float m_run[2][4], l_run[2][4];
  #pragma unroll
  for (int m = 0; m < 2; ++m)
    #pragma unroll
    for (int r = 0; r < 4; ++r) { m_run[m][r] = -3e38f; l_run[m][r] = 0.f; }

  unsigned short* Psw = &Ps[wave][0];
  const int vkey = wave * 16 + (lane >> 2);
  const int vd0 = (lane & 3) * 16;

  for (int c = 0; c < 3; ++c) {
    const int wk = w + c - 1;
    if (wk < 0 || wk >= NW) {
      // 128 pad keys, k=v=(-1,...,-1), UNMASKED (reference semantics)
      #pragma unroll
      for (int m = 0; m < 2; ++m)
        #pragma unroll
        for (int r = 0; r < 4; ++r) {
          const float sp = -qsum[m][r];
          const float mn = fmaxf(m_run[m][r], sp);
          const float scale = __expf(m_run[m][r] - mn);
          const float pe = __expf(sp - mn) * 128.f;
          l_run[m][r] = l_run[m][r] * scale + pe;
          m_run[m][r] = mn;
          #pragma unroll
          for (int nd = 0; nd < 4; ++nd)
            acc[m][nd][r] = acc[m][nd][r] * scale - pe;
        }
      continue;
    }
    for (int ch = 0; ch < 2; ++ch) {
      __syncthreads();   // previous chunk compute done before overwrite
      // stage K chunk (gload_lds, pre-swizzled src)
      const unsigned short* Kg =
          Kb + head_off + (size_t)(wk * WSZ + ch * 64) * HD;
      #pragma unroll
      for (int i = 0; i < 2; ++i) {
        const int cc = wave * 2 + i;
        gload_lds16(Kg + (size_t)(cc * 8 + rsub) * HD + bsub, &Ks[cc * 512]);
      }
      // stage V chunk transposed -> Vt[d][key] (reg-staged, swizzled writes)
      {
        const unsigned short* Vg =
            Vb + head_off + (size_t)(wk * WSZ + ch * 64) * HD;
        const ushort8 v0 = *(const ushort8*)&Vg[vkey * HD + vd0];
        const ushort8 v1 = *(const ushort8*)&Vg[vkey * HD + vd0 + 8];
        #pragma unroll
        for (int j = 0; j < 8; ++j) {
          int d = vd0 + j;
          *(unsigned short*)((char*)Vt + ((d * 128 + vkey * 2) ^ ((d & 7) << 4))) = v0[j];
          d = vd0 + 8 + j;
          *(unsigned short*)((char*)Vt + ((d * 128 + vkey * 2) ^ ((d & 7) << 4))) = v1[j];
        }
      }
      __syncthreads();   // staged (compiler drains vmcnt+lgkmcnt)

      // --- QK^T: S[q][key], contraction over d ---
      f32x4 s[2][4] = {};
      #pragma unroll
      for (int ks = 0; ks < 2; ++ks) {
        const bf16x8 aq0 = lds_frag(Qs, q0 + li, ks * 32 + gl * 8);
        const bf16x8 aq1 = lds_frag(Qs, q0 + 16 + li, ks * 32 + gl * 8);
        #pragma unroll
        for (int n = 0; n < 4; ++n) {
          const bf16x8 bk = lds_frag(Ks, n * 16 + li, ks * 32 + gl * 8);
          s[0][n] = __builtin_amdgcn_mfma_f32_16x16x32_bf16(aq0, bk, s[0][n], 0, 0, 0);
          s[1][n] = __builtin_amdgcn_mfma_f32_16x16x32_bf16(aq1, bk, s[1][n], 0, 0, 0);
        }
      }
      // --- mask (c=0: key<q bad; c=2: key>q bad) ---
      if (c != 1) {
        #pragma unroll
        for (int m = 0; m < 2; ++m)
          #pragma unroll
          for (int n = 0; n < 4; ++n)
            #pragma unroll
            for (int r = 0; r < 4; ++r) {
              const int q_in = q0 + m * 16 + gl * 4 + r;
              const int k_in = ch * 64 + n * 16 + li;
              const bool bad = (c == 0) ? (k_in < q_in) : (k_in > q_in);
              if (bad) s[m][n][r] = -3e38f;
            }
      }
      // --- online softmax (row spread over 16 lanes of the lane-group) ---
      #pragma unroll
      for (int m = 0; m < 2; ++m) {
        float mx[4], sc[4], rs[4];
        #pragma unroll
        for (int r = 0; r < 4; ++r)
          mx[r] = fmaxf(fmaxf(s[m][0][r], s[m][1][r]),
                        fmaxf(s[m][2][r], s[m][3][r]));
        #pragma unroll
        for (int off = 1; off < 16; off <<= 1)
          #pragma unroll
          for (int r = 0; r < 4; ++r)
            mx[r] = fmaxf(mx[r], __shfl_xor(mx[r], off));
        #pragma unroll
        for (int r = 0; r < 4; ++r) {
          const float mn = fmaxf(m_run[m][r], mx[r]);
          sc[r] = __expf(m_run[m][r] - mn);
          m_run[m][r] = mn;
          rs[r] = 0.f;
        }
        #pragma unroll
        for (int n = 0; n < 4; ++n)
          #pragma unroll
          for (int r = 0; r < 4; ++r) {
            const float v = s[m][n][r];
            const float p = (v > -1e30f) ? __expf(v - m_run[m][r]) : 0.f;
            s[m][n][r] = p;
            rs[r] += p;
          }
        #pragma unroll
        for (int off = 1; off < 16; off <<= 1)
          #pragma unroll
          for (int r = 0; r < 4; ++r)
            rs[r] += __shfl_xor(rs[r], off);
        #pragma unroll
        for (int r = 0; r < 4; ++r)
          l_run[m][r] = l_run[m][r] * sc[r] + rs[r];
        #pragma unroll
        for (int nd = 0; nd < 4; ++nd)
          #pragma unroll
          for (int r = 0; r < 4; ++r)
            acc[m][nd][r] *= sc[r];
      }
      // --- P -> LDS bf16 [32][72] (per-wave, stride-72 = conflict-light) ---
      #pragma unroll
      for (int m = 0; m < 2; ++m)
        #pragma unroll
        for (int n = 0; n < 4; ++n)
          #pragma unroll
          for (int r = 0; r < 4; ++r)
            Psw[(m * 16 + gl * 4 + r) * 72 + n * 16 + li] = f2bf(s[m][n][r]);
      // --- PV: O += P * V, contraction over key ---
      #pragma unroll
      for (int ks = 0; ks < 2; ++ks) {
        const bf16x8 ap0 = *(const bf16x8*)&Psw[(li) * 72 + ks * 32 + gl * 8];
        const bf16x8 ap1 = *(const bf16x8*)&Psw[(16 + li) * 72 + ks * 32 + gl * 8];
        #pragma unroll
        for (int nd = 0; nd < 4; ++nd) {
          const bf16x8 bv = lds_frag(Vt, nd * 16 + li, ks * 32 + gl * 8);
          acc[0][nd] = __builtin_amdgcn_mfma_f32_16x16x32_bf16(ap0, bv, acc[0][nd], 0, 0, 0);
          acc[1][nd] = __builtin_amdgcn_mfma_f32_16x16x32_bf16(ap1, bv, acc[1][nd], 0, 0, 0);
        }
      }
    }
  }

  // --- normalize + write out fp32 [b][s][h*64+d] ---
  const int b = bh >> 4, h = bh & 15;
  #pragma unroll
  for (int m = 0; m < 2; ++m) {
    float inv[4];
    #pragma unroll
    for (int r = 0; r < 4; ++r) inv[r] = 1.f / l_run[m][r];
    #pragma unroll
    for (int nd = 0; nd < 4; ++nd)
      #pragma unroll
      for (int r = 0; r < 4; ++r) {
        const int q = q0 + m * 16 + gl * 4 + r;
        out[((size_t)(b * Sn + w * WSZ + q)) * En + h * HD + nd * 16 + li] =
            acc[m][nd][r] * inv[r];
      }
  }
}

// ---------------------------------------------------------------------------
extern "C" void kernel_launch(void* const* d_in, const int* in_sizes, int n_in,
                              void* d_out, int out_size, void* d_ws,
                              size_t ws_size, hipStream_t stream) {
  const float* x    = (const float*)d_in[0];
  const float* wqkv = (const float*)d_in[1];
  const float* bqkv = (const float*)d_in[2];
  float* out = (float*)d_out;

  // ws layout (ushort units): Qb | Kb | Vb | xb | wb  = 140.5 MB total
  unsigned short* ws = (unsigned short*)d_ws;
  const size_t HT = (size_t)Bn * Hn * Sn * HD;   // 16.78M elems per tensor
  unsigned short* Qb = ws;
  unsigned short* Kb = ws + HT;
  unsigned short* Vb = ws + 2 * HT;
  unsigned short* xb = ws + 3 * HT;
  unsigned short* wb = ws + 3 * HT + (size_t)Mr * Kd;

  cvt_x<<<(Mr * Kd) / (256 * 8), 256, 0, stream>>>(x, xb);
  dim3 gw(N3 / 32, Kd / 32);
  cvt_wT<<<gw, 256, 0, stream>>>(wqkv, wb);

  dim3 g1(N3 / TN, Mr / TM);
  qkv_gemm_bf16<<<g1, 256, 0, stream>>>(xb, wb, bqkv, Qb, Kb, Vb);

  dim3 g2(NW, Bn * Hn);
  attn_mfma<<<g2, 256, 0, stream>>>(Qb, Kb, Vb, out);
}

// Round 4
// 386.814 us; speedup vs baseline: 3.0174x; 1.0750x over previous
//
#include <hip/hip_runtime.h>
#include <hip/hip_bf16.h>
#include <cmath>

// Problem constants
constexpr int Bn  = 4;
constexpr int Sn  = 4096;
constexpr int En  = 1024;
constexpr int Hn  = 16;
constexpr int HD  = 64;
constexpr int WSZ = 128;
constexpr int NW  = Sn / WSZ;   // 32
constexpr int Mr  = Bn * Sn;    // 16384 rows
constexpr int N3  = 3 * En;     // 3072
constexpr int Kd  = En;         // 1024

typedef __attribute__((ext_vector_type(8))) short  bf16x8;
typedef __attribute__((ext_vector_type(4))) float  f32x4;
typedef __attribute__((ext_vector_type(8))) unsigned short ushort8;

__device__ __forceinline__ unsigned short f2bf(float f) {
  __hip_bfloat16 h = __float2bfloat16(f);   // RTNE
  return *reinterpret_cast<unsigned short*>(&h);
}

__device__ __forceinline__ void gload_lds16(const void* g, void* l) {
  __builtin_amdgcn_global_load_lds(
      (const __attribute__((address_space(1))) void*)g,
      (__attribute__((address_space(3))) void*)l, 16, 0, 0);
}

// ---------------------------------------------------------------------------
// cvt_x: x fp32 [16384,1024] -> bf16 (row-major)
// ---------------------------------------------------------------------------
__global__ __launch_bounds__(256) void cvt_x(const float* __restrict__ x,
                                             unsigned short* __restrict__ xb) {
  const int i = (blockIdx.x * 256 + threadIdx.x) * 8;
  const float4 a = *(const float4*)&x[i];
  const float4 b = *(const float4*)&x[i + 4];
  ushort8 o;
  o[0] = f2bf(a.x); o[1] = f2bf(a.y); o[2] = f2bf(a.z); o[3] = f2bf(a.w);
  o[4] = f2bf(b.x); o[5] = f2bf(b.y); o[6] = f2bf(b.z); o[7] = f2bf(b.w);
  *(ushort8*)&xb[i] = o;
}

// ---------------------------------------------------------------------------
// cvt_wT: W fp32 [K=1024][N=3072] -> Wt bf16 [N=3072][K=1024]  (transpose)
// ---------------------------------------------------------------------------
__global__ __launch_bounds__(256) void cvt_wT(const float* __restrict__ W,
                                              unsigned short* __restrict__ Wt) {
  __shared__ float t[32][33];
  const int bx = blockIdx.x * 32;          // n base
  const int by = blockIdx.y * 32;          // k base
  const int tx = threadIdx.x & 31;
  const int ty = threadIdx.x >> 5;
  #pragma unroll
  for (int i = 0; i < 32; i += 8)
    t[ty + i][tx] = W[(size_t)(by + ty + i) * N3 + bx + tx];
  __syncthreads();
  #pragma unroll
  for (int i = 0; i < 32; i += 8)
    Wt[(size_t)(bx + ty + i) * Kd + by + tx] = f2bf(t[tx][ty + i]);
}

// ---------------------------------------------------------------------------
// cvt_vT: Vb bf16 [bh][s][64] -> VT bf16 [bh][64][s]  (per-head transpose)
// Coalesced global on both sides; LDS tile 64x64 (stride 72).
// ---------------------------------------------------------------------------
__global__ __launch_bounds__(256) void cvt_vT(const unsigned short* __restrict__ V,
                                              unsigned short* __restrict__ VT) {
  __shared__ unsigned short t[64][72];
  const int s0 = blockIdx.x * 64;
  const int bh = blockIdx.y;
  const unsigned short* Vg = V + ((size_t)bh * Sn + s0) * HD;
  const int r  = threadIdx.x >> 3;          // 0..31
  const int c8 = (threadIdx.x & 7) * 8;
  *(ushort8*)&t[r][c8]      = *(const ushort8*)&Vg[(size_t)r * HD + c8];
  *(ushort8*)&t[r + 32][c8] = *(const ushort8*)&Vg[(size_t)(r + 32) * HD + c8];
  __syncthreads();
  unsigned short* Og = VT + (size_t)bh * HD * Sn + s0;
  const int d = threadIdx.x >> 3;           // 0..31
  ushort8 o0, o1;
  #pragma unroll
  for (int j = 0; j < 8; ++j) { o0[j] = t[c8 + j][d]; o1[j] = t[c8 + j][d + 32]; }
  *(ushort8*)&Og[(size_t)d * Sn + c8]        = o0;
  *(ushort8*)&Og[(size_t)(d + 32) * Sn + c8] = o1;
}

// ---------------------------------------------------------------------------
// qkv_gemm_bf16 (m97 structure, unchanged from R3 — verified)
// ---------------------------------------------------------------------------
constexpr int TM = 128, TN = 128, TK = 32;

__global__ __launch_bounds__(256) void qkv_gemm_bf16(
    const unsigned short* __restrict__ Abf,   // [Mr][Kd]
    const unsigned short* __restrict__ Bt,    // [N3][Kd]
    const float* __restrict__ bias,
    unsigned short* __restrict__ Qb, unsigned short* __restrict__ Kb,
    unsigned short* __restrict__ Vb) {
  __shared__ unsigned short As[TM * TK];
  __shared__ unsigned short Bs[TN * TK];

  const int tid  = threadIdx.x;
  const int wave = tid >> 6;
  const int lane = tid & 63;
  const int bm = blockIdx.y * TM;
  const int bn = blockIdx.x * TN;
  const int wr = wave >> 1, wc = wave & 1;

  f32x4 acc[4][4] = {};

  const int sr  = lane >> 2;
  const int sc8 = (lane & 3) * 8;
  const int fr = lane & 15;
  const int fk = (lane >> 4) * 8;

  for (int k0 = 0; k0 < Kd; k0 += TK) {
    #pragma unroll
    for (int i = 0; i < 2; ++i) {
      const int c = wave * 2 + i;
      gload_lds16(Abf + (size_t)(bm + c * 16 + sr) * Kd + k0 + sc8, &As[c * 512]);
      gload_lds16(Bt  + (size_t)(bn + c * 16 + sr) * Kd + k0 + sc8, &Bs[c * 512]);
    }
    __syncthreads();
    bf16x8 af[4], bfr[4];
    #pragma unroll
    for (int m = 0; m < 4; ++m)
      af[m] = *(const bf16x8*)&As[(wr * 64 + m * 16 + fr) * TK + fk];
    #pragma unroll
    for (int n = 0; n < 4; ++n)
      bfr[n] = *(const bf16x8*)&Bs[(wc * 64 + n * 16 + fr) * TK + fk];
    #pragma unroll
    for (int m = 0; m < 4; ++m)
      #pragma unroll
      for (int n = 0; n < 4; ++n)
        acc[m][n] = __builtin_amdgcn_mfma_f32_16x16x32_bf16(
            af[m], bfr[n], acc[m][n], 0, 0, 0);
    __syncthreads();
  }

  const int col0 = bn + wc * 64 + (lane & 15);
  const int row0 = bm + wr * 64 + (lane >> 4) * 4;
  #pragma unroll
  for (int n = 0; n < 4; ++n) {
    const int col = col0 + n * 16;
    const float bv = bias[col];
    const int which = col >> 10;           // 0=q 1=k 2=v (wave-uniform)
    const int h = (col >> 6) & 15;
    const int d = col & 63;
    unsigned short* T = (which == 0) ? Qb : (which == 1) ? Kb : Vb;
    #pragma unroll
    for (int m = 0; m < 4; ++m)
      #pragma unroll
      for (int r = 0; r < 4; ++r) {
        const int row = row0 + m * 16 + r;
        const int b = row >> 12;
        const int s = row & 4095;
        T[((size_t)((b << 4) + h) * Sn + s) * HD + d] =
            f2bf(acc[m][n][r] + bv);
      }
  }
}

// ---------------------------------------------------------------------------
// attn_mfma: flash-style local attention, MFMA 16x16x32 bf16.
// R4: Q frags in registers; K and V^T both staged via global_load_lds with
// pre-swizzled source (rule #21); double-buffered chunks, ONE barrier per
// chunk (T3-lite); setprio around MFMA clusters (T5).
// ---------------------------------------------------------------------------
__global__ __launch_bounds__(256) void attn_mfma(
    const unsigned short* __restrict__ Qb,
    const unsigned short* __restrict__ Kb,
    const unsigned short* __restrict__ VT,
    float* __restrict__ out) {
  __shared__ unsigned short Ks[2][64 * 64];   // 16 KB (rows = key)
  __shared__ unsigned short Vs[2][64 * 64];   // 16 KB (rows = d)
  __shared__ unsigned short Ps[4][32 * 72];   // 18 KB

  const int w   = blockIdx.x;
  const int bh  = blockIdx.y;
  const int tid = threadIdx.x, wave = tid >> 6, lane = tid & 63;
  const int gl = lane >> 4, li = lane & 15;
  const int q0 = wave * 32;

  const size_t head_off = (size_t)bh * Sn * HD;
  const unsigned short* Qg  = Qb + head_off + (size_t)w * WSZ * HD;
  const unsigned short* Kg0 = Kb + head_off;
  const unsigned short* Vg0 = VT + (size_t)bh * HD * Sn;

  // --- Q fragments in registers (A-operand layout, m89/m91-verified) ---
  bf16x8 qf[2][2];
  #pragma unroll
  for (int m = 0; m < 2; ++m)
    #pragma unroll
    for (int ks = 0; ks < 2; ++ks)
      qf[m][ks] = *(const bf16x8*)
          &Qg[(size_t)(q0 + m * 16 + li) * HD + ks * 32 + gl * 8];

  bf16x8 ones;
  #pragma unroll
  for (int j = 0; j < 8; ++j) ones[j] = (short)0x3F80;   // bf16 1.0
  f32x4 qsum[2] = {};
  #pragma unroll
  for (int m = 0; m < 2; ++m)
    #pragma unroll
    for (int ks = 0; ks < 2; ++ks)
      qsum[m] = __builtin_amdgcn_mfma_f32_16x16x32_bf16(
          qf[m][ks], ones, qsum[m], 0, 0, 0);

  f32x4 acc[2][4] = {};
  float m_run[2][4], l_run[2][4];
  #pragma unroll
  for (int m = 0; m < 2; ++m)
    #pragma unroll
    for (int r = 0; r < 4; ++r) { m_run[m][r] = -3e38f; l_run[m][r] = 0.f; }

  // --- pad windows (reference: 128 unmasked all-(-1) K/V rows) ---
  if (w == 0 || w == NW - 1) {
    #pragma unroll
    for (int m = 0; m < 2; ++m)
      #pragma unroll
      for (int r = 0; r < 4; ++r) {
        const float sp = -qsum[m][r];
        const float mn = fmaxf(m_run[m][r], sp);
        const float scale = __expf(m_run[m][r] - mn);
        const float pe = __expf(sp - mn) * 128.f;
        l_run[m][r] = l_run[m][r] * scale + pe;
        m_run[m][r] = mn;
        #pragma unroll
        for (int nd = 0; nd < 4; ++nd)
          acc[m][nd][r] = acc[m][nd][r] * scale - pe;
      }
  }

  // valid neighbor windows
  int vw[3], nv = 0;
  #pragma unroll
  for (int c = 0; c < 3; ++c) {
    const int wk = w + c - 1;
    if (0 <= wk && wk < NW) vw[nv++] = wk;
  }
  const int T = 2 * nv;

  const int rsub  = lane >> 3;
  const int ebsub = ((lane & 7) ^ rsub) * 8;   // pre-swizzled elem offset

  auto stage = [&](int t, int buf) {
    const int wk = vw[t >> 1];
    const int s0 = wk * WSZ + (t & 1) * 64;
    #pragma unroll
    for (int i = 0; i < 2; ++i) {
      const int cc = wave * 2 + i;
      gload_lds16(Kg0 + (size_t)(s0 + cc * 8 + rsub) * HD + ebsub,
                  &Ks[buf][cc * 512]);
      gload_lds16(Vg0 + (size_t)(cc * 8 + rsub) * Sn + s0 + ebsub,
                  &Vs[buf][cc * 512]);
    }
  };

  // swizzled frag read: row-major [row][64] bf16, XOR ((row&7)<<4)
  auto lds_frag = [&](const unsigned short* base, int row, int kpos) {
    return *(const bf16x8*)((const char*)base + row * 128 +
                            ((kpos * 2) ^ ((row & 7) << 4)));
  };

  unsigned short* Psw = &Ps[wave][0];

  stage(0, 0);
  __syncthreads();

  for (int t = 0; t < T; ++t) {
    const int buf = t & 1;
    if (t + 1 < T) stage(t + 1, buf ^ 1);   // in flight during compute

    const int wk = vw[t >> 1];
    const int c  = wk - w + 1;              // 0,1,2
    const int ch = t & 1;

    // --- QK^T ---
    f32x4 s[2][4] = {};
    __builtin_amdgcn_s_setprio(1);
    #pragma unroll
    for (int ks = 0; ks < 2; ++ks) {
      #pragma unroll
      for (int n = 0; n < 4; ++n) {
        const bf16x8 bk = lds_frag(&Ks[buf][0], n * 16 + li, ks * 32 + gl * 8);
        s[0][n] = __builtin_amdgcn_mfma_f32_16x16x32_bf16(qf[0][ks], bk, s[0][n], 0, 0, 0);
        s[1][n] = __builtin_amdgcn_mfma_f32_16x16x32_bf16(qf[1][ks], bk, s[1][n], 0, 0, 0);
      }
    }
    __builtin_amdgcn_s_setprio(0);

    // --- mask ---
    if (c != 1) {
      #pragma unroll
      for (int m = 0; m < 2; ++m)
        #pragma unroll
        for (int n = 0; n < 4; ++n)
          #pragma unroll
          for (int r = 0; r < 4; ++r) {
            const int q_in = q0 + m * 16 + gl * 4 + r;
            const int k_in = ch * 64 + n * 16 + li;
            const bool bad = (c == 0) ? (k_in < q_in) : (k_in > q_in);
            if (bad) s[m][n][r] = -3e38f;
          }
    }

    // --- online softmax (16-lane group owns a row) ---
    #pragma unroll
    for (int m = 0; m < 2; ++m) {
      float mx[4], sc[4], rs[4];
      #pragma unroll
      for (int r = 0; r < 4; ++r)
        mx[r] = fmaxf(fmaxf(s[m][0][r], s[m][1][r]),
                      fmaxf(s[m][2][r], s[m][3][r]));
      #pragma unroll
      for (int off = 1; off < 16; off <<= 1)
        #pragma unroll
        for (int r = 0; r < 4; ++r)
          mx[r] = fmaxf(mx[r], __shfl_xor(mx[r], off));
      #pragma unroll
      for (int r = 0; r < 4; ++r) {
        const float mn = fmaxf(m_run[m][r], mx[r]);
        sc[r] = __expf(m_run[m][r] - mn);
        m_run[m][r] = mn;
        rs[r] = 0.f;
      }
      #pragma unroll
      for (int n = 0; n < 4; ++n)
        #pragma unroll
        for (int r = 0; r < 4; ++r) {
          const float v = s[m][n][r];
          const float p = (v > -1e30f) ? __expf(v - m_run[m][r]) : 0.f;
          s[m][n][r] = p;
          rs[r] += p;
        }
      #pragma unroll
      for (int off = 1; off < 16; off <<= 1)
        #pragma unroll
        for (int r = 0; r < 4; ++r)
          rs[r] += __shfl_xor(rs[r], off);
      #pragma unroll
      for (int r = 0; r < 4; ++r)
        l_run[m][r] = l_run[m][r] * sc[r] + rs[r];
      #pragma unroll
      for (int nd = 0; nd < 4; ++nd)
        #pragma unroll
        for (int r = 0; r < 4; ++r)
          acc[m][nd][r] *= sc[r];
    }

    // --- P -> LDS bf16 (per-wave, stride 72) ---
    #pragma unroll
    for (int m = 0; m < 2; ++m)
      #pragma unroll
      for (int n = 0; n < 4; ++n)
        #pragma unroll
        for (int r = 0; r < 4; ++r)
          Psw[(m * 16 + gl * 4 + r) * 72 + n * 16 + li] = f2bf(s[m][n][r]);

    // --- PV ---
    __builtin_amdgcn_s_setprio(1);
    #pragma unroll
    for (int ks = 0; ks < 2; ++ks) {
      const bf16x8 ap0 = *(const bf16x8*)&Psw[(li) * 72 + ks * 32 + gl * 8];
      const bf16x8 ap1 = *(const bf16x8*)&Psw[(16 + li) * 72 + ks * 32 + gl * 8];
      #pragma unroll
      for (int nd = 0; nd < 4; ++nd) {
        const bf16x8 bv = lds_frag(&Vs[buf][0], nd * 16 + li, ks * 32 + gl * 8);
        acc[0][nd] = __builtin_amdgcn_mfma_f32_16x16x32_bf16(ap0, bv, acc[0][nd], 0, 0, 0);
        acc[1][nd] = __builtin_amdgcn_mfma_f32_16x16x32_bf16(ap1, bv, acc[1][nd], 0, 0, 0);
      }
    }
    __builtin_amdgcn_s_setprio(0);

    __syncthreads();   // drains next-chunk loads; releases buf for t+2 stage
  }

  // --- normalize + write out fp32 [b][s][h*64+d] ---
  const int b = bh >> 4, h = bh & 15;
  #pragma unroll
  for (int m = 0; m < 2; ++m) {
    float inv[4];
    #pragma unroll
    for (int r = 0; r < 4; ++r) inv[r] = 1.f / l_run[m][r];
    #pragma unroll
    for (int nd = 0; nd < 4; ++nd)
      #pragma unroll
      for (int r = 0; r < 4; ++r) {
        const int q = q0 + m * 16 + gl * 4 + r;
        out[((size_t)(b * Sn + w * WSZ + q)) * En + h * HD + nd * 16 + li] =
            acc[m][nd][r] * inv[r];
      }
  }
}

// ---------------------------------------------------------------------------
extern "C" void kernel_launch(void* const* d_in, const int* in_sizes, int n_in,
                              void* d_out, int out_size, void* d_ws,
                              size_t ws_size, hipStream_t stream) {
  const float* x    = (const float*)d_in[0];
  const float* wqkv = (const float*)d_in[1];
  const float* bqkv = (const float*)d_in[2];
  float* out = (float*)d_out;

  // ws layout (ushort units): Qb | Kb | Vb | VT | xb | wb  = ~174 MB
  unsigned short* ws = (unsigned short*)d_ws;
  const size_t HT = (size_t)Bn * Hn * Sn * HD;   // 16.78M elems per tensor
  unsigned short* Qb = ws;
  unsigned short* Kb = ws + HT;
  unsigned short* Vb = ws + 2 * HT;
  unsigned short* VTt = ws + 3 * HT;
  unsigned short* xb = ws + 4 * HT;
  unsigned short* wb = ws + 4 * HT + (size_t)Mr * Kd;

  cvt_x<<<(Mr * Kd) / (256 * 8), 256, 0, stream>>>(x, xb);
  dim3 gw(N3 / 32, Kd / 32);
  cvt_wT<<<gw, 256, 0, stream>>>(wqkv, wb);

  dim3 g1(N3 / TN, Mr / TM);
  qkv_gemm_bf16<<<g1, 256, 0, stream>>>(xb, wb, bqkv, Qb, Kb, Vb);

  dim3 gv(Sn / 64, Bn * Hn);
  cvt_vT<<<gv, 256, 0, stream>>>(Vb, VTt);

  dim3 g2(NW, Bn * Hn);
  attn_mfma<<<g2, 256, 0, stream>>>(Qb, Kb, VTt, out);
}